// Round 5
// baseline (151.666 us; speedup 1.0000x reference)
//
#include <hip/hip_runtime.h>

typedef __attribute__((ext_vector_type(8))) short short8;
typedef __attribute__((ext_vector_type(4))) float f32x4;

#define GROUP_ELEMS 2097152     // 2 channels * 64*128*128
#define NBLK 64

__device__ inline short f2bf(float f) {
  unsigned u = __builtin_bit_cast(unsigned, f);
  unsigned r = (u + 0x7FFFu + ((u >> 16) & 1u)) >> 16;
  return (short)r;
}

__device__ inline void gload_lds16(const void* g, void* l) {
  __builtin_amdgcn_global_load_lds(
      (const __attribute__((address_space(1))) unsigned int*)g,
      (__attribute__((address_space(3))) unsigned int*)l, 16, 0, 0);
}

__global__ __launch_bounds__(256) void k1_partials(const float* __restrict__ x,
                                                   float2* __restrict__ partials) {
  int group = blockIdx.x >> 6;
  int blk = blockIdx.x & 63;
  const float4* p = (const float4*)(x + (size_t)group * GROUP_ELEMS + (size_t)blk * 32768);
  float sum = 0.f, sq = 0.f;
  for (int i = threadIdx.x; i < 8192; i += 256) {
    float4 v = p[i];
    sum += v.x + v.y + v.z + v.w;
    sq  += v.x*v.x + v.y*v.y + v.z*v.z + v.w*v.w;
  }
  for (int off = 32; off; off >>= 1) {
    sum += __shfl_down(sum, off, 64);
    sq  += __shfl_down(sq,  off, 64);
  }
  __shared__ float2 sw[4];
  int lane = threadIdx.x & 63, wid = threadIdx.x >> 6;
  if (lane == 0) sw[wid] = make_float2(sum, sq);
  __syncthreads();
  if (threadIdx.x == 0) {
    float s = 0.f, q = 0.f;
    for (int j = 0; j < 4; ++j) { s += sw[j].x; q += sw[j].y; }
    partials[blockIdx.x] = make_float2(s, q);
  }
}

__global__ void k2_stats(const float2* __restrict__ partials,
                         float2* __restrict__ stats, int* __restrict__ hist) {
  int t = threadIdx.x;
  if (t < 16) {
    float s = 0.f, q = 0.f;
    for (int j = 0; j < NBLK; ++j) { float2 p = partials[t * NBLK + j]; s += p.x; q += p.y; }
    float mean = s / (float)GROUP_ELEMS;
    float var  = q / (float)GROUP_ELEMS - mean * mean;
    stats[t] = make_float2(mean, rsqrtf(var + 1e-5f));
  }
  if (t < 21) hist[t] = 0;
}

// repack conv weights into plane-major (2D-tap) MFMA B-fragment layout:
// frag f = kd*5 + c (kd=0..2, c=0..4); tap t = 2c + (lane>>5), t in [0,9), 9 = pad
// fbw2[(f*64+lane)*8 + j] = bf16(W[oc=lane&15][ic=((lane>>4)&1)*8+j][kd][kh=t/3][kw=t%3])
// also zeroes the 64-B dummy region used by k4's OOB halo loads.
__global__ void k2b_wprep(const float* __restrict__ wgt, unsigned short* __restrict__ fbw2,
                          unsigned int* __restrict__ dummy) {
  int t = threadIdx.x;             // 1024 threads; 960 = 15 frags * 64 lanes
  if (t < 960) {
    int f = t >> 6, lane = t & 63;
    int kd = f / 5, c = f - kd * 5;
    int m = lane & 15, g = lane >> 4;
    int icb = (g & 1) * 8, g2 = g >> 1;
    int tap = 2 * c + g2;          // 0..9
    short8 v;
    #pragma unroll
    for (int j = 0; j < 8; ++j)
      v[j] = (tap <= 8) ? f2bf(wgt[m * 432 + (icb + j) * 27 + kd * 9 + tap]) : (short)0;
    *(short8*)(fbw2 + t * 8) = v;
  }
  if (t >= 960 && t < 976) dummy[t - 960] = 0;
}

// GroupNorm+ReLU+hist+threshold, f32x4-vectorized (G13). Thread = (cp = t>>5,
// 4 hw at hwl = t&31). ALL 8 channel-pairs live in the SAME block so z's
// [hw][ic=16] 64-B lines are fully written by co-resident threads in the same
// d-iteration. d-axis in 4 chunks of 16 (bootstrap read at lo-1 feeds the
// sequential threshold recurrence).
__global__ __launch_bounds__(256) void k3_norm_thresh_hist(
    const float* __restrict__ x, const float* __restrict__ gw, const float* __restrict__ gb,
    const float* __restrict__ thrp, const float2* __restrict__ stats,
    unsigned short* __restrict__ z, int* __restrict__ hist) {
  __shared__ int sh[21];
  int t = threadIdx.x;
  if (t < 21) sh[t] = 0;
  __syncthreads();
  int bx = blockIdx.x;
  int b = bx >> 9, part = (bx >> 2) & 127, dchunk = bx & 3;
  int cp = t >> 5, hwl = t & 31;
  int hw = part * 128 + hwl * 4;
  int c0 = cp * 2, c1 = c0 + 1;
  float2 st = stats[b * 8 + cp];
  float A0 = gw[c0] * st.y, B0 = gb[c0] - st.x * A0;
  float A1 = gw[c1] * st.y, B1 = gb[c1] - st.x * A1;
  float thr = thrp[0];
  const f32x4* px0 = (const f32x4*)(x + (size_t)(b * 16 + c0) * 1048576 + hw);
  const f32x4* px1 = (const f32x4*)(x + (size_t)(b * 16 + c1) * 1048576 + hw);
  unsigned* pz = (unsigned*)(z + ((size_t)b * 1048576 + hw) * 16 + c0);
  int c10 = 0, c11 = 0, c12 = 0;
  const int lo = dchunk * 16, dend = lo + 16;
  const int dstart = (lo == 0) ? 0 : lo - 1;
  f32x4 xv0 = px0[(size_t)dstart * 4096], xv1 = px1[(size_t)dstart * 4096];
  float yp0[4], yp1[4];
  for (int d = dstart; d < dend; ++d) {
    f32x4 n0 = {0.f,0.f,0.f,0.f}, n1 = {0.f,0.f,0.f,0.f};
    if (d + 1 < dend) { n0 = px0[(size_t)(d + 1) * 4096]; n1 = px1[(size_t)(d + 1) * 4096]; }
    bool act = (d >= lo);
    #pragma unroll
    for (int k = 0; k < 4; ++k) {
      float y0 = fmaxf(fmaf(xv0[k], A0, B0), 0.f);
      float y1 = fmaxf(fmaf(xv1[k], A1, B1), 0.f);
      if (act) {
        float v0 = ceilf(0.5f * y0);
        if (v0 == 0.f) c10++; else if (v0 == 1.f) c11++; else if (v0 == 2.f) c12++;
        else if (v0 <= 10.f) atomicAdd(&sh[(int)v0 + 10], 1);
        float v1 = ceilf(0.5f * y1);
        if (v1 == 0.f) c10++; else if (v1 == 1.f) c11++; else if (v1 == 2.f) c12++;
        else if (v1 <= 10.f) atomicAdd(&sh[(int)v1 + 10], 1);
        float z0, z1;
        if (d == 0) { z0 = y0; z1 = y1; }
        else {
          float dd0 = (y0 - yp0[k]) / thr;
          z0 = (fabsf(dd0) > 1.f) ? fmaf(dd0, thr, yp0[k]) : yp0[k];
          float dd1 = (y1 - yp1[k]) / thr;
          z1 = (fabsf(dd1) > 1.f) ? fmaf(dd1, thr, yp1[k]) : yp1[k];
        }
        unsigned u = (unsigned)(unsigned short)f2bf(z0) | ((unsigned)(unsigned short)f2bf(z1) << 16);
        pz[d * 131072 + k * 8] = u;
      }
      yp0[k] = y0; yp1[k] = y1;
    }
    xv0 = n0; xv1 = n1;
  }
  atomicAdd(&sh[10], c10);
  atomicAdd(&sh[11], c11);
  atomicAdd(&sh[12], c12);
  __syncthreads();
  if (t < 21) atomicAdd(&hist[t], sh[t]);
}

// MFMA implicit-GEMM conv, PLANE-MAJOR, T3+T4 pipelined.
// Each A-fragment is ds_read ONCE, used by 3 MFMAs (kd=0,1,2 -> 3 rotating acc
// sets). 3-slot LDS ring (32,640 B), slot = plane%3. Per body:
//   issue DMA(ph+1) -> slot (SC+1)%3
//   s_waitcnt vmcnt(L)   (L = THIS wave's just-issued loads: 2 or 1)
//                        -> completes plane-ph DMA + older stores, LEAVES the
//                           new loads in flight across the barrier (T4)
//   raw s_barrier (no vmcnt(0) drain, unlike __syncthreads)
//   compute plane ph from slot SC; store finished dout.
// Epoch safety needs 3 slots: issue(ph+1) is barrier-concurrent with
// compute(ph-1); (ph+1)-(ph-1) = 2 mod 3 -> disjoint. Last reader of the
// overwritten slot is two barriers back. sched_barrier(0) + "memory" clobbers
// fence hipcc from hoisting ds_reads across the barrier (it sees no LDS
// writes at all with global_load_lds). Math identical to R4 -> absmax must
// stay exactly 0.2216797; any drift = race.
#define DT 8
#define PLANE 5440          // 10*34*16 ushorts = 10,880 B per plane slot
__global__ __launch_bounds__(512, 4) void k4_conv(const unsigned short* __restrict__ z,
                                                  const unsigned short* __restrict__ fbw2,
                                                  const char* __restrict__ dummyc,
                                                  float* __restrict__ out) {
  __shared__ unsigned short lz[3 * PLANE];   // 32,640 B
  const int t = threadIdx.x;
  const int lane = t & 63, wid = t >> 6;     // 8 waves
  const int b = blockIdx.z;
  const int d0 = blockIdx.y * DT;
  const int h0 = (blockIdx.x >> 2) * 8, w0 = (blockIdx.x & 3) * 32;
  const int m = lane & 15, g = lane >> 4;
  const int icb = (g & 1) * 8, g2 = g >> 1;

  // weights: 15 B-fragments (kd*5 + c), register-resident (60 VGPR)
  short8 fb2[15];
  #pragma unroll
  for (int f = 0; f < 15; ++f)
    fb2[f] = *(const short8*)(fbw2 + (f * 64 + lane) * 8);

  // per-lane A-read tap offsets (ushort units) for c = 0..4
  int tco[5];
  #pragma unroll
  for (int c = 0; c < 5; ++c) {
    int tap = 2 * c + g2; if (tap > 8) tap = 8;
    tco[c] = ((tap / 3) * 34 + (tap % 3)) * 16;
  }

  const char* zbc = (const char*)(z + (size_t)b * 16777216);   // bytes base

  // staging: 680 granules/plane. chunk A: granule = t (waves 0-7, 512).
  // chunk B: wid0 -> 512+, wid1 -> 576+, wid2 -> 616+ (616-639 double-written
  // with identical data); waves 3-7 idle on chunk B.
  const int cbA = wid * 64;
  const int cbB = (wid == 0) ? 512 : (wid == 1) ? 576 : 616;
  const bool hasB = (wid < 3);
  long long hobA, hobB; bool hvA, hvB;
  {
    int gi, r, rem, s, ig, hg, wg;
    gi = cbA + lane; r = gi / 68; rem = gi - r * 68; s = rem >> 1; ig = rem & 1;
    hg = h0 - 1 + r; wg = w0 - 1 + s;
    hvA = ((unsigned)hg < 128u) && ((unsigned)wg < 128u);
    hobA = ((long long)(hg * 128 + wg) * 16 + ig * 8) * 2;
    gi = cbB + lane; r = gi / 68; rem = gi - r * 68; s = rem >> 1; ig = rem & 1;
    hg = h0 - 1 + r; wg = w0 - 1 + s;
    hvB = ((unsigned)hg < 128u) && ((unsigned)wg < 128u);
    hobB = ((long long)(hg * 128 + wg) * 16 + ig * 8) * 2;
  }

  const f32x4 fzero = {0.f, 0.f, 0.f, 0.f};
  f32x4 A0[2], A1[2], A2[2];
  #pragma unroll
  for (int q = 0; q < 2; ++q) { A0[q] = fzero; A1[q] = fzero; A2[q] = fzero; }

  // prologue: issue DMA for plane 0 (global d = d0-1) into slot 0. No barrier:
  // BODY(0)'s counted wait + raw barrier covers it.
  {
    const int dg = d0 - 1;
    const long long dgo = (long long)dg * 524288;
    const bool pd = (unsigned)dg < 64u;
    gload_lds16((pd && hvA) ? zbc + dgo + hobA : dummyc, &lz[cbA * 8]);
    if (hasB)
      gload_lds16((pd && hvB) ? zbc + dgo + hobB : dummyc, &lz[cbB * 8]);
  }

  // BODY(ph, SC): SC = ph%3 (compile-time at each expansion).
#define BODY(PH, SC, AS, AM, AN, DOJ2, DOJ1, DOJ0, DOLOAD, DOSTORE)                     \
  {                                                                                     \
    const int ph_ = (PH);                                                               \
    if (DOLOAD) {                                                                       \
      const int dg = d0 + ph_;     /* plane ph+1 holds global d = d0+ph */              \
      const long long dgo = (long long)dg * 524288;                                     \
      const bool pd = (unsigned)dg < 64u;                                               \
      const unsigned sl = (unsigned)(((SC) + 1) % 3) * PLANE;                           \
      gload_lds16((pd && hvA) ? zbc + dgo + hobA : dummyc, &lz[sl + cbA * 8]);          \
      if (hasB)                                                                         \
        gload_lds16((pd && hvB) ? zbc + dgo + hobB : dummyc, &lz[sl + cbB * 8]);        \
      if (hasB) asm volatile("s_waitcnt vmcnt(2)" ::: "memory");                        \
      else      asm volatile("s_waitcnt vmcnt(1)" ::: "memory");                        \
    } else {                                                                            \
      asm volatile("s_waitcnt vmcnt(0)" ::: "memory");                                  \
    }                                                                                   \
    __builtin_amdgcn_sched_barrier(0);                                                  \
    __builtin_amdgcn_s_barrier();                                                       \
    __builtin_amdgcn_sched_barrier(0);                                                  \
    const unsigned su = (unsigned)(SC) * PLANE;                                         \
    __builtin_amdgcn_s_setprio(1);                                                      \
    _Pragma("unroll")                                                                   \
    for (int q = 0; q < 2; ++q) {                                                       \
      const int hl = wid, wt = q;                                                       \
      const int qb = (hl * 34 + wt * 16 + m) * 16 + icb + (int)su;                      \
      _Pragma("unroll")                                                                 \
      for (int c = 0; c < 5; ++c) {                                                     \
        short8 a = *(const short8*)(&lz[qb + tco[c]]);                                  \
        if (DOJ2) AN[q] = __builtin_amdgcn_mfma_f32_16x16x32_bf16(a, fb2[c], AN[q], 0, 0, 0);      \
        if (DOJ1) AM[q] = __builtin_amdgcn_mfma_f32_16x16x32_bf16(a, fb2[5 + c], AM[q], 0, 0, 0);  \
        if (DOJ0) AS[q] = __builtin_amdgcn_mfma_f32_16x16x32_bf16(a, fb2[10 + c], AS[q], 0, 0, 0); \
      }                                                                                 \
    }                                                                                   \
    __builtin_amdgcn_s_setprio(0);                                                      \
    if (DOSTORE) {                                                                      \
      const int dd = d0 + ph_ - 2;                                                      \
      _Pragma("unroll")                                                                 \
      for (int q = 0; q < 2; ++q) {                                                     \
        const int hl = wid, wt = q;                                                     \
        float* op = out + (((size_t)(b * 16 + m) * 64 + dd) * 128 + (h0 + hl)) * 128    \
                    + w0 + wt * 16 + g * 4;                                             \
        *(float4*)op = make_float4(AS[q][0], AS[q][1], AS[q][2], AS[q][3]);             \
        AS[q] = fzero;                                                                  \
      }                                                                                 \
    }                                                                                   \
  }

  // peel: planes 0,1 skip j's that would target out-of-block depths
  BODY(0, 0, A1, A2, A0, 1, 0, 0, 1, 0)
  BODY(1, 1, A2, A0, A1, 1, 1, 0, 1, 0)
  BODY(2, 2, A0, A1, A2, 1, 1, 1, 1, 1)
  #pragma unroll 1
  for (int pp = 3; pp <= 6; pp += 3) {     // pp = 3, 6: pp%3 == 0
    BODY(pp,     0, A1, A2, A0, 1, 1, 1, 1, 1)
    BODY(pp + 1, 1, A2, A0, A1, 1, 1, 1, 1, 1)
    BODY(pp + 2, 2, A0, A1, A2, 1, 1, 1, 1, 1)
  }
  // tail: plane 9 (slot 0) only finishes dout d0+7 (j0); no further loads
  BODY(9, 0, A1, A2, A0, 0, 0, 1, 0, 1)
#undef BODY
}

__global__ void k5_hist_out(const int* __restrict__ hist, float* __restrict__ out) {
  int t = threadIdx.x;
  if (t < 21) out[33554432u + t] = (float)hist[t] * (100.0f / 33554432.0f);
}

extern "C" void kernel_launch(void* const* d_in, const int* in_sizes, int n_in,
                              void* d_out, int out_size, void* d_ws, size_t ws_size,
                              hipStream_t stream) {
  (void)in_sizes; (void)n_in; (void)out_size; (void)ws_size;
  const float* x   = (const float*)d_in[0];
  const float* gw  = (const float*)d_in[1];
  const float* gb  = (const float*)d_in[2];
  const float* thr = (const float*)d_in[3];
  const float* cw  = (const float*)d_in[4];
  float* out = (float*)d_out;

  char* ws = (char*)d_ws;
  unsigned short* z = (unsigned short*)ws;                               // 64 MiB bf16
  float2* partials  = (float2*)(ws + (size_t)67108864);                  // 8 KiB
  float2* stats     = (float2*)(ws + (size_t)67108864 + 8192);           // 128 B
  int*    hist      = (int*)  (ws + (size_t)67108864 + 8192 + 128);      // 84 B
  unsigned int* dummy = (unsigned int*)(ws + (size_t)67108864 + 8448);   // 64 B zeros
  unsigned short* fbw2 = (unsigned short*)(ws + (size_t)67108864 + 16384); // 15,360 B

  k1_partials<<<1024, 256, 0, stream>>>(x, partials);
  k2_stats<<<1, 64, 0, stream>>>(partials, stats, hist);
  k2b_wprep<<<1, 1024, 0, stream>>>(cw, fbw2, dummy);
  k3_norm_thresh_hist<<<1024, 256, 0, stream>>>(x, gw, gb, thr, stats, z, hist);
  k4_conv<<<dim3(64, 8, 2), 512, 0, stream>>>(z, fbw2, (const char*)dummy, out);
  k5_hist_out<<<1, 64, 0, stream>>>(hist, out);
}

// Round 6
// 151.121 us; speedup vs baseline: 1.0036x; 1.0036x over previous
//
#include <hip/hip_runtime.h>

typedef __attribute__((ext_vector_type(8))) short short8;
typedef __attribute__((ext_vector_type(4))) float f32x4;

#define GROUP_ELEMS 2097152     // 2 channels * 64*128*128
#define NBLK 64

__device__ inline short f2bf(float f) {
  unsigned u = __builtin_bit_cast(unsigned, f);
  unsigned r = (u + 0x7FFFu + ((u >> 16) & 1u)) >> 16;
  return (short)r;
}

__global__ __launch_bounds__(256) void k1_partials(const float* __restrict__ x,
                                                   float2* __restrict__ partials) {
  int group = blockIdx.x >> 6;
  int blk = blockIdx.x & 63;
  const float4* p = (const float4*)(x + (size_t)group * GROUP_ELEMS + (size_t)blk * 32768);
  float sum = 0.f, sq = 0.f;
  for (int i = threadIdx.x; i < 8192; i += 256) {
    float4 v = p[i];
    sum += v.x + v.y + v.z + v.w;
    sq  += v.x*v.x + v.y*v.y + v.z*v.z + v.w*v.w;
  }
  for (int off = 32; off; off >>= 1) {
    sum += __shfl_down(sum, off, 64);
    sq  += __shfl_down(sq,  off, 64);
  }
  __shared__ float2 sw[4];
  int lane = threadIdx.x & 63, wid = threadIdx.x >> 6;
  if (lane == 0) sw[wid] = make_float2(sum, sq);
  __syncthreads();
  if (threadIdx.x == 0) {
    float s = 0.f, q = 0.f;
    for (int j = 0; j < 4; ++j) { s += sw[j].x; q += sw[j].y; }
    partials[blockIdx.x] = make_float2(s, q);
  }
}

// merged: group stats + hist zero + conv-weight repack (tap-major MFMA
// B-fragment layout, 14 frags: fbw[(cc*64+lane)*8+j] =
// bf16(W[oc=lane&15][ic=((lane>>4)&1)*8+j][kpos=2cc+(lane>>5)])). one launch.
__global__ void k2_prep(const float2* __restrict__ partials, const float* __restrict__ wgt,
                        float2* __restrict__ stats, int* __restrict__ hist,
                        unsigned short* __restrict__ fbw) {
  int t = threadIdx.x;             // 896 = 14 cc * 64 lanes
  if (t < 16) {
    float s = 0.f, q = 0.f;
    for (int j = 0; j < NBLK; ++j) { float2 p = partials[t * NBLK + j]; s += p.x; q += p.y; }
    float mean = s / (float)GROUP_ELEMS;
    float var  = q / (float)GROUP_ELEMS - mean * mean;
    stats[t] = make_float2(mean, rsqrtf(var + 1e-5f));
  }
  if (t < 21) hist[t] = 0;
  int cc = t >> 6, lane = t & 63;
  int m = lane & 15, g = lane >> 4;
  int icb = (g & 1) * 8, g2 = g >> 1;
  int kpos = 2 * cc + g2;
  short8 f;
  #pragma unroll
  for (int j = 0; j < 8; ++j)
    f[j] = (kpos <= 26) ? f2bf(wgt[m * 432 + (icb + j) * 27 + kpos]) : (short)0;
  *(short8*)(fbw + t * 8) = f;
}

// GroupNorm+ReLU+hist+threshold, f32x4-vectorized (G13). Thread = (cp = t>>5,
// 4 hw at hwl = t&31). ALL 8 channel-pairs in the SAME block so z's [hw][ic=16]
// 64-B lines are fully written by co-resident threads in the same d-iteration.
// d-axis in 4 chunks of 16 (bootstrap read at lo-1 feeds the recurrence).
__global__ __launch_bounds__(256) void k3_norm_thresh_hist(
    const float* __restrict__ x, const float* __restrict__ gw, const float* __restrict__ gb,
    const float* __restrict__ thrp, const float2* __restrict__ stats,
    unsigned short* __restrict__ z, int* __restrict__ hist) {
  __shared__ int sh[21];
  int t = threadIdx.x;
  if (t < 21) sh[t] = 0;
  __syncthreads();
  int bx = blockIdx.x;
  int b = bx >> 9, part = (bx >> 2) & 127, dchunk = bx & 3;
  int cp = t >> 5, hwl = t & 31;
  int hw = part * 128 + hwl * 4;
  int c0 = cp * 2, c1 = c0 + 1;
  float2 st = stats[b * 8 + cp];
  float A0 = gw[c0] * st.y, B0 = gb[c0] - st.x * A0;
  float A1 = gw[c1] * st.y, B1 = gb[c1] - st.x * A1;
  float thr = thrp[0];
  const f32x4* px0 = (const f32x4*)(x + (size_t)(b * 16 + c0) * 1048576 + hw);
  const f32x4* px1 = (const f32x4*)(x + (size_t)(b * 16 + c1) * 1048576 + hw);
  unsigned* pz = (unsigned*)(z + ((size_t)b * 1048576 + hw) * 16 + c0);
  int c10 = 0, c11 = 0, c12 = 0;
  const int lo = dchunk * 16, dend = lo + 16;
  const int dstart = (lo == 0) ? 0 : lo - 1;
  f32x4 xv0 = px0[(size_t)dstart * 4096], xv1 = px1[(size_t)dstart * 4096];
  float yp0[4], yp1[4];
  for (int d = dstart; d < dend; ++d) {
    f32x4 n0 = {0.f,0.f,0.f,0.f}, n1 = {0.f,0.f,0.f,0.f};
    if (d + 1 < dend) { n0 = px0[(size_t)(d + 1) * 4096]; n1 = px1[(size_t)(d + 1) * 4096]; }
    bool act = (d >= lo);
    #pragma unroll
    for (int k = 0; k < 4; ++k) {
      float y0 = fmaxf(fmaf(xv0[k], A0, B0), 0.f);
      float y1 = fmaxf(fmaf(xv1[k], A1, B1), 0.f);
      if (act) {
        float v0 = ceilf(0.5f * y0);
        if (v0 == 0.f) c10++; else if (v0 == 1.f) c11++; else if (v0 == 2.f) c12++;
        else if (v0 <= 10.f) atomicAdd(&sh[(int)v0 + 10], 1);
        float v1 = ceilf(0.5f * y1);
        if (v1 == 0.f) c10++; else if (v1 == 1.f) c11++; else if (v1 == 2.f) c12++;
        else if (v1 <= 10.f) atomicAdd(&sh[(int)v1 + 10], 1);
        float z0, z1;
        if (d == 0) { z0 = y0; z1 = y1; }
        else {
          float dd0 = (y0 - yp0[k]) / thr;
          z0 = (fabsf(dd0) > 1.f) ? fmaf(dd0, thr, yp0[k]) : yp0[k];
          float dd1 = (y1 - yp1[k]) / thr;
          z1 = (fabsf(dd1) > 1.f) ? fmaf(dd1, thr, yp1[k]) : yp1[k];
        }
        unsigned u = (unsigned)(unsigned short)f2bf(z0) | ((unsigned)(unsigned short)f2bf(z1) << 16);
        pz[d * 131072 + k * 8] = u;
      }
      yp0[k] = y0; yp1[k] = y1;
    }
    xv0 = n0; xv1 = n1;
  }
  atomicAdd(&sh[10], c10);
  atomicAdd(&sh[11], c11);
  atomicAdd(&sh[12], c12);
  __syncthreads();
  if (t < 21) atomicAdd(&hist[t], sh[t]);
}

// MFMA implicit-GEMM conv — R2's proven tap-major structure (141.7 µs session
// best). Tile = 8d x 8h x 32w, 256 thr (4 waves), 3-plane LDS ring (32,640 B,
// 4 blocks/CU), reg-staged T14 (issue global loads before compute, ds_write
// after barrier), two __syncthreads per dl. Swizzle: granule-half bit ig XORed
// with bit2 of w-position s (both sides). k5 folded in: block (0,0,0) writes
// the 21 hist outputs (ready since k3) — saves a launch.
#define DT 8
#define PLANE 5440          // 10*34*16 ushorts = 10,880 B per plane slot
__global__ __launch_bounds__(256, 4) void k4_conv(const unsigned short* __restrict__ z,
                                                  const unsigned short* __restrict__ fbw,
                                                  const int* __restrict__ hist,
                                                  float* __restrict__ out) {
  __shared__ unsigned short lz[3 * PLANE];   // 32,640 B
  const int t = threadIdx.x;
  if (blockIdx.x == 0 && blockIdx.y == 0 && blockIdx.z == 0 && t < 21)
    out[33554432u + t] = (float)hist[t] * (100.0f / 33554432.0f);
  const int lane = t & 63, wid = t >> 6;
  const int b = blockIdx.z;
  const int d0 = blockIdx.y * DT;
  const int h0 = (blockIdx.x >> 2) * 8, w0 = (blockIdx.x & 3) * 32;
  const int m = lane & 15, g = lane >> 4;
  const int icb = (g & 1) * 8;
  const bool gs = (g >= 2);
  // per-lane swizzle XOR constants for tap kw = 0,1,2 (ushort units, bit 3)
  const int xw0 = ((m >> 2) & 1) << 3;
  const int xw1 = (((m + 1) >> 2) & 1) << 3;
  const int xw2 = (((m + 2) >> 2) & 1) << 3;

  short8 fb[14];
  #pragma unroll
  for (int cc = 0; cc < 14; ++cc)
    fb[cc] = *(const short8*)(fbw + (cc * 64 + lane) * 8);

  const unsigned short* zb = z + (size_t)b * 16777216;   // 64*16384*16

  // per-thread staging coords (dl-invariant). chunk i handles granule
  // gi = t + 256*i within a 680-granule plane (10 rows x 34 s x 2 halves).
  const int gi0 = t,        r0 = gi0 / 68, rm0 = gi0 - r0 * 68, s0 = rm0 >> 1, ig0 = rm0 & 1;
  const int gi1 = t + 256,  r1 = gi1 / 68, rm1 = gi1 - r1 * 68, s1 = rm1 >> 1, ig1 = rm1 & 1;
  const int gi2 = t + 512,  r2 = gi2 / 68, rm2 = gi2 - r2 * 68, s2 = rm2 >> 1, ig2 = rm2 & 1;
  const int hg0 = h0 - 1 + r0, wg0 = w0 - 1 + s0;
  const int hg1 = h0 - 1 + r1, wg1 = w0 - 1 + s1;
  const int hg2 = h0 - 1 + r2, wg2 = w0 - 1 + s2;
  const bool va0 = (unsigned)hg0 < 128u && (unsigned)wg0 < 128u;
  const bool va1 = (unsigned)hg1 < 128u && (unsigned)wg1 < 128u;
  const bool va2 = t < 168 && (unsigned)hg2 < 128u && (unsigned)wg2 < 128u;
  const int gof0 = (hg0 * 128 + wg0) * 16 + ig0 * 8;
  const int gof1 = (hg1 * 128 + wg1) * 16 + ig1 * 8;
  const int gof2 = (hg2 * 128 + wg2) * 16 + ig2 * 8;
  const int io0 = (r0 * 34 + s0) * 16 + (ig0 ^ ((s0 >> 2) & 1)) * 8;
  const int io1 = (r1 * 34 + s1) * 16 + (ig1 ^ ((s1 >> 2) & 1)) * 8;
  const int io2 = (r2 * 34 + s2) * 16 + (ig2 ^ ((s2 >> 2) & 1)) * 8;

  // prologue: stage planes p=0..2 (global d = d0-1 .. d0+1) into slots 0..2
  #pragma unroll
  for (int p = 0; p < 3; ++p) {
    const int dg = d0 - 1 + p;
    const bool dv = (unsigned)dg < 64u;
    short8 v0 = {0,0,0,0,0,0,0,0}, v1 = {0,0,0,0,0,0,0,0}, v2 = {0,0,0,0,0,0,0,0};
    if (dv && va0) v0 = *(const short8*)(zb + dg * 262144 + gof0);
    if (dv && va1) v1 = *(const short8*)(zb + dg * 262144 + gof1);
    if (dv && va2) v2 = *(const short8*)(zb + dg * 262144 + gof2);
    *(short8*)(&lz[p * PLANE + io0]) = v0;
    *(short8*)(&lz[p * PLANE + io1]) = v1;
    if (t < 168) *(short8*)(&lz[p * PLANE + io2]) = v2;
  }
  __syncthreads();

  int sA = 0, sB = PLANE, sC = 2 * PLANE;   // slots of planes dl, dl+1, dl+2

  #pragma unroll 1
  for (int dl = 0; dl < DT; ++dl) {
    // T14 stage-issue: plane dl+3 (global d = d0+dl+2) -> will overwrite slot sA
    short8 sv0 = {0,0,0,0,0,0,0,0}, sv1 = {0,0,0,0,0,0,0,0}, sv2 = {0,0,0,0,0,0,0,0};
    const bool doStage = dl < DT - 1;
    if (doStage) {
      const int dg = d0 + dl + 2;
      const bool dv = (unsigned)dg < 64u;
      if (dv && va0) sv0 = *(const short8*)(zb + dg * 262144 + gof0);
      if (dv && va1) sv1 = *(const short8*)(zb + dg * 262144 + gof1);
      if (dv && va2) sv2 = *(const short8*)(zb + dg * 262144 + gof2);
    }
    // compute dl: 4 tiles per wave (hl = wid*2+(q>>1), wt = q&1), 14 MFMA each
    #pragma unroll
    for (int q = 0; q < 4; ++q) {
      const int hl = wid * 2 + (q >> 1), wt = q & 1;
      const int qb = (hl * 34 + wt * 16 + m) * 16 + icb;
      f32x4 acc = {0.f, 0.f, 0.f, 0.f};
      __builtin_amdgcn_s_setprio(1);
      #pragma unroll
      for (int cc = 0; cc < 14; ++cc) {
        const int kp0 = 2 * cc;
        const int kp1 = (2 * cc + 1 > 26) ? 26 : 2 * cc + 1;
        const int kd0 = kp0 / 9, kh0 = (kp0 % 9) / 3, kw0 = kp0 % 3;
        const int kd1 = kp1 / 9, kh1 = (kp1 % 9) / 3, kw1 = kp1 % 3;
        const int co0 = (kh0 * 34 + kw0) * 16;
        const int co1 = (kh1 * 34 + kw1) * 16;
        const int ba0 = (kd0 == 0) ? sA : (kd0 == 1) ? sB : sC;
        const int ba1 = (kd1 == 0) ? sA : (kd1 == 1) ? sB : sC;
        const int xk0 = (kw0 == 0) ? xw0 : (kw0 == 1) ? xw1 : xw2;
        const int xk1 = (kw1 == 0) ? xw0 : (kw1 == 1) ? xw1 : xw2;
        const int off0 = (qb ^ xk0) + co0 + ba0;
        const int off1 = (qb ^ xk1) + co1 + ba1;
        const int off = gs ? off1 : off0;
        short8 a = *(const short8*)(&lz[off]);
        acc = __builtin_amdgcn_mfma_f32_16x16x32_bf16(a, fb[cc], acc, 0, 0, 0);
      }
      __builtin_amdgcn_s_setprio(0);
      float* op = out + (((size_t)(b * 16 + m) * 64 + (d0 + dl)) * 128 + (h0 + hl)) * 128
                  + w0 + wt * 16 + g * 4;
      *(float4*)op = make_float4(acc[0], acc[1], acc[2], acc[3]);
    }
    __syncthreads();            // all waves done reading plane dl (slot sA)
    if (doStage) {
      *(short8*)(&lz[sA + io0]) = sv0;
      *(short8*)(&lz[sA + io1]) = sv1;
      if (t < 168) *(short8*)(&lz[sA + io2]) = sv2;
      __syncthreads();          // plane dl+3 visible before compute dl+1
    }
    const int tmp = sA; sA = sB; sB = sC; sC = tmp;
  }
}

extern "C" void kernel_launch(void* const* d_in, const int* in_sizes, int n_in,
                              void* d_out, int out_size, void* d_ws, size_t ws_size,
                              hipStream_t stream) {
  (void)in_sizes; (void)n_in; (void)out_size; (void)ws_size;
  const float* x   = (const float*)d_in[0];
  const float* gw  = (const float*)d_in[1];
  const float* gb  = (const float*)d_in[2];
  const float* thr = (const float*)d_in[3];
  const float* cw  = (const float*)d_in[4];
  float* out = (float*)d_out;

  char* ws = (char*)d_ws;
  unsigned short* z = (unsigned short*)ws;                               // 64 MiB bf16
  float2* partials  = (float2*)(ws + (size_t)67108864);                  // 8 KiB
  float2* stats     = (float2*)(ws + (size_t)67108864 + 8192);           // 128 B
  int*    hist      = (int*)  (ws + (size_t)67108864 + 8192 + 128);      // 84 B
  unsigned short* fbw = (unsigned short*)(ws + (size_t)67108864 + 16384); // 14,336 B

  k1_partials<<<1024, 256, 0, stream>>>(x, partials);
  k2_prep<<<1, 896, 0, stream>>>(partials, cw, stats, hist, fbw);
  k3_norm_thresh_hist<<<1024, 256, 0, stream>>>(x, gw, gb, thr, stats, z, hist);
  k4_conv<<<dim3(64, 8, 2), 256, 0, stream>>>(z, fbw, hist, out);
}

// Round 7
// 133.610 us; speedup vs baseline: 1.1351x; 1.1311x over previous
//
#include <hip/hip_runtime.h>

typedef __attribute__((ext_vector_type(8))) short short8;
typedef __attribute__((ext_vector_type(4))) float f32x4;

#define GROUP_ELEMS 2097152     // 2 channels * 64*128*128
#define NBLK 64

__device__ inline short f2bf(float f) {
  unsigned u = __builtin_bit_cast(unsigned, f);
  unsigned r = (u + 0x7FFFu + ((u >> 16) & 1u)) >> 16;
  return (short)r;
}

__device__ inline void gload_lds16(const void* g, void* l) {
  __builtin_amdgcn_global_load_lds(
      (const __attribute__((address_space(1))) unsigned int*)g,
      (__attribute__((address_space(3))) unsigned int*)l, 16, 0, 0);
}

__global__ __launch_bounds__(256) void k1_partials(const float* __restrict__ x,
                                                   float2* __restrict__ partials) {
  int group = blockIdx.x >> 6;
  int blk = blockIdx.x & 63;
  const float4* p = (const float4*)(x + (size_t)group * GROUP_ELEMS + (size_t)blk * 32768);
  float sum = 0.f, sq = 0.f;
  for (int i = threadIdx.x; i < 8192; i += 256) {
    float4 v = p[i];
    sum += v.x + v.y + v.z + v.w;
    sq  += v.x*v.x + v.y*v.y + v.z*v.z + v.w*v.w;
  }
  for (int off = 32; off; off >>= 1) {
    sum += __shfl_down(sum, off, 64);
    sq  += __shfl_down(sq,  off, 64);
  }
  __shared__ float2 sw[4];
  int lane = threadIdx.x & 63, wid = threadIdx.x >> 6;
  if (lane == 0) sw[wid] = make_float2(sum, sq);
  __syncthreads();
  if (threadIdx.x == 0) {
    float s = 0.f, q = 0.f;
    for (int j = 0; j < 4; ++j) { s += sw[j].x; q += sw[j].y; }
    partials[blockIdx.x] = make_float2(s, q);
  }
}

// merged prep: group stats + hist zero + dummy zero + plane-major conv-weight
// repack. frag f = kd*5 + c (kd=0..2, c=0..4); tap = 2c + (lane>>5) (9 = pad):
// fbw2[(f*64+lane)*8+j] = bf16(W[oc=lane&15][ic=((lane>>4)&1)*8+j][kd][tap/3][tap%3])
__global__ void k2_prep(const float2* __restrict__ partials, const float* __restrict__ wgt,
                        float2* __restrict__ stats, int* __restrict__ hist,
                        unsigned short* __restrict__ fbw2, unsigned int* __restrict__ dummy) {
  int t = threadIdx.x;             // 1024 threads; 960 = 15 frags * 64 lanes
  if (t < 16) {
    float s = 0.f, q = 0.f;
    for (int j = 0; j < NBLK; ++j) { float2 p = partials[t * NBLK + j]; s += p.x; q += p.y; }
    float mean = s / (float)GROUP_ELEMS;
    float var  = q / (float)GROUP_ELEMS - mean * mean;
    stats[t] = make_float2(mean, rsqrtf(var + 1e-5f));
  }
  if (t < 21) hist[t] = 0;
  if (t < 960) {
    int f = t >> 6, lane = t & 63;
    int kd = f / 5, c = f - kd * 5;
    int m = lane & 15, g = lane >> 4;
    int icb = (g & 1) * 8, g2 = g >> 1;
    int tap = 2 * c + g2;          // 0..9
    short8 v;
    #pragma unroll
    for (int j = 0; j < 8; ++j)
      v[j] = (tap <= 8) ? f2bf(wgt[m * 432 + (icb + j) * 27 + kd * 9 + tap]) : (short)0;
    *(short8*)(fbw2 + t * 8) = v;
  }
  if (t >= 960 && t < 976) dummy[t - 960] = 0;
}

// GroupNorm+ReLU+hist+threshold — R2's SCALAR version (measured best; the
// f32x4 restructure cost +12 µs: redundant bootstrap rows, 4x stride-32B
// stores, broken 1-deep prefetch. Scalar is already coalesced 128B/half-wave
// and TLP-saturated). Thread per (b, hw, channel-pair): 1024 blocks x 256 thr.
__global__ __launch_bounds__(256) void k3_norm_thresh_hist(
    const float* __restrict__ x, const float* __restrict__ gw, const float* __restrict__ gb,
    const float* __restrict__ thrp, const float2* __restrict__ stats,
    unsigned short* __restrict__ z, int* __restrict__ hist) {
  __shared__ int sh[21];
  int t = threadIdx.x;
  if (t < 21) sh[t] = 0;
  __syncthreads();
  int hwl = t & 31, cp = t >> 5;
  int b = blockIdx.x >> 9;
  int hw = (blockIdx.x & 511) * 32 + hwl;
  int c0 = cp * 2, c1 = c0 + 1;
  float2 st = stats[b * 8 + cp];
  float A0 = gw[c0] * st.y, B0 = gb[c0] - st.x * A0;
  float A1 = gw[c1] * st.y, B1 = gb[c1] - st.x * A1;
  float thr = thrp[0];
  const float* px0 = x + (size_t)(b * 16 + c0) * 1048576 + hw;
  const float* px1 = x + (size_t)(b * 16 + c1) * 1048576 + hw;
  unsigned* pz = (unsigned*)(z + ((size_t)b * 64 * 16384 + hw) * 16 + c0);
  int c10 = 0, c11 = 0, c12 = 0;
  float xv0 = px0[0], xv1 = px1[0];
  float yp0 = 0.f, yp1 = 0.f;
  for (int d = 0; d < 64; ++d) {
    float n0 = 0.f, n1 = 0.f;
    if (d < 63) { n0 = px0[(d + 1) * 16384]; n1 = px1[(d + 1) * 16384]; }
    float y0 = fmaxf(fmaf(xv0, A0, B0), 0.f);
    float y1 = fmaxf(fmaf(xv1, A1, B1), 0.f);
    float v0 = ceilf(0.5f * y0);
    if (v0 == 0.f) c10++; else if (v0 == 1.f) c11++; else if (v0 == 2.f) c12++;
    else if (v0 <= 10.f) atomicAdd(&sh[(int)v0 + 10], 1);
    float v1 = ceilf(0.5f * y1);
    if (v1 == 0.f) c10++; else if (v1 == 1.f) c11++; else if (v1 == 2.f) c12++;
    else if (v1 <= 10.f) atomicAdd(&sh[(int)v1 + 10], 1);
    float z0, z1;
    if (d == 0) { z0 = y0; z1 = y1; }
    else {
      float dd0 = (y0 - yp0) / thr;
      z0 = (fabsf(dd0) > 1.f) ? fmaf(dd0, thr, yp0) : yp0;
      float dd1 = (y1 - yp1) / thr;
      z1 = (fabsf(dd1) > 1.f) ? fmaf(dd1, thr, yp1) : yp1;
    }
    unsigned u = (unsigned)(unsigned short)f2bf(z0) | ((unsigned)(unsigned short)f2bf(z1) << 16);
    pz[d * 131072] = u;
    yp0 = y0; yp1 = y1;
    xv0 = n0; xv1 = n1;
  }
  atomicAdd(&sh[10], c10);
  atomicAdd(&sh[11], c11);
  atomicAdd(&sh[12], c12);
  __syncthreads();
  if (t < 21) atomicAdd(&hist[t], sh[t]);
}

// MFMA implicit-GEMM conv — R4's plane-major 512-thr version (measured ~7 µs
// faster than tap-major once k3 confound removed). Each A-fragment ds_read
// ONCE, used by 3 MFMAs (kd=0,1,2 -> 3 rotating acc sets). 2-slot LDS double
// buffer (21,760 B), staging via global_load_lds, one __syncthreads per plane
// (R5 proved counted-vmcnt regresses here). 8 waves, 2 q-subtiles/wave ->
// fits 128-VGPR budget of launch_bounds(512,4). OOB halo lanes load a zeroed
// dummy region. k5 folded in: block (0,0,0) writes the 21 hist outputs.
#define DT 8
#define PLANE 5440          // 10*34*16 ushorts = 10,880 B per plane slot
__global__ __launch_bounds__(512, 4) void k4_conv(const unsigned short* __restrict__ z,
                                                  const unsigned short* __restrict__ fbw2,
                                                  const char* __restrict__ dummyc,
                                                  const int* __restrict__ hist,
                                                  float* __restrict__ out) {
  __shared__ unsigned short lz[2 * PLANE];   // 21,760 B
  const int t = threadIdx.x;
  if (blockIdx.x == 0 && blockIdx.y == 0 && blockIdx.z == 0 && t < 21)
    out[33554432u + t] = (float)hist[t] * (100.0f / 33554432.0f);
  const int lane = t & 63, wid = t >> 6;     // 8 waves
  const int b = blockIdx.z;
  const int d0 = blockIdx.y * DT;
  const int h0 = (blockIdx.x >> 2) * 8, w0 = (blockIdx.x & 3) * 32;
  const int m = lane & 15, g = lane >> 4;
  const int icb = (g & 1) * 8, g2 = g >> 1;

  // weights: 15 B-fragments (kd*5 + c), register-resident (60 VGPR)
  short8 fb2[15];
  #pragma unroll
  for (int f = 0; f < 15; ++f)
    fb2[f] = *(const short8*)(fbw2 + (f * 64 + lane) * 8);

  // per-lane A-read tap offsets (ushort units) for c = 0..4
  int tco[5];
  #pragma unroll
  for (int c = 0; c < 5; ++c) {
    int tap = 2 * c + g2; if (tap > 8) tap = 8;
    tco[c] = ((tap / 3) * 34 + (tap % 3)) * 16;
  }

  const char* zbc = (const char*)(z + (size_t)b * 16777216);   // bytes base

  // staging: 680 granules/plane. chunk A: granule = t (waves 0-7, 512).
  // chunk B: wid0 -> 512+, wid1 -> 576+, wid2 -> 616+ (616-639 double-written
  // with identical data); waves 3-7 idle on chunk B.
  const int cbA = wid * 64;
  const int cbB = (wid == 0) ? 512 : (wid == 1) ? 576 : 616;
  const bool hasB = (wid < 3);
  long long hobA, hobB; bool hvA, hvB;
  {
    int gi, r, rem, s, ig, hg, wg;
    gi = cbA + lane; r = gi / 68; rem = gi - r * 68; s = rem >> 1; ig = rem & 1;
    hg = h0 - 1 + r; wg = w0 - 1 + s;
    hvA = ((unsigned)hg < 128u) && ((unsigned)wg < 128u);
    hobA = ((long long)(hg * 128 + wg) * 16 + ig * 8) * 2;
    gi = cbB + lane; r = gi / 68; rem = gi - r * 68; s = rem >> 1; ig = rem & 1;
    hg = h0 - 1 + r; wg = w0 - 1 + s;
    hvB = ((unsigned)hg < 128u) && ((unsigned)wg < 128u);
    hobB = ((long long)(hg * 128 + wg) * 16 + ig * 8) * 2;
  }

  const f32x4 fzero = {0.f, 0.f, 0.f, 0.f};
  f32x4 A0[2], A1[2], A2[2];
  #pragma unroll
  for (int q = 0; q < 2; ++q) { A0[q] = fzero; A1[q] = fzero; A2[q] = fzero; }

  // prologue: stage plane 0 (global d = d0-1) into slot 0
  {
    const int dg = d0 - 1;
    const long long dgo = (long long)dg * 524288;
    const bool pd = (unsigned)dg < 64u;
    gload_lds16((pd && hvA) ? zbc + dgo + hobA : dummyc, &lz[cbA * 8]);
    if (hasB)
      gload_lds16((pd && hvB) ? zbc + dgo + hobB : dummyc, &lz[cbB * 8]);
  }
  __syncthreads();

  // BODY(ph): issue loads for plane ph+1 -> slot (ph+1)&1; compute plane ph
  // from slot ph&1 (j2 -> AN [kd=0], j1 -> AM [kd=1], j0 -> AS [kd=2]);
  // store AS (dout = d0+ph-2); barrier.
#define BODY(PH, AS, AM, AN, DOJ2, DOJ1, DOJ0, DOLOAD, DOSTORE)                         \
  {                                                                                     \
    const int ph_ = (PH);                                                               \
    if (DOLOAD) {                                                                       \
      const int dg = d0 + ph_;                                                          \
      const long long dgo = (long long)dg * 524288;                                     \
      const bool pd = (unsigned)dg < 64u;                                               \
      const unsigned sl = ((unsigned)(ph_ + 1) & 1u) * PLANE;                           \
      gload_lds16((pd && hvA) ? zbc + dgo + hobA : dummyc, &lz[sl + cbA * 8]);          \
      if (hasB)                                                                         \
        gload_lds16((pd && hvB) ? zbc + dgo + hobB : dummyc, &lz[sl + cbB * 8]);        \
    }                                                                                   \
    const unsigned su = ((unsigned)ph_ & 1u) * PLANE;                                   \
    __builtin_amdgcn_s_setprio(1);                                                      \
    _Pragma("unroll")                                                                   \
    for (int q = 0; q < 2; ++q) {                                                       \
      const int hl = wid, wt = q;                                                       \
      const int qb = (hl * 34 + wt * 16 + m) * 16 + icb + (int)su;                      \
      _Pragma("unroll")                                                                 \
      for (int c = 0; c < 5; ++c) {                                                     \
        short8 a = *(const short8*)(&lz[qb + tco[c]]);                                  \
        if (DOJ2) AN[q] = __builtin_amdgcn_mfma_f32_16x16x32_bf16(a, fb2[c], AN[q], 0, 0, 0);      \
        if (DOJ1) AM[q] = __builtin_amdgcn_mfma_f32_16x16x32_bf16(a, fb2[5 + c], AM[q], 0, 0, 0);  \
        if (DOJ0) AS[q] = __builtin_amdgcn_mfma_f32_16x16x32_bf16(a, fb2[10 + c], AS[q], 0, 0, 0); \
      }                                                                                 \
    }                                                                                   \
    __builtin_amdgcn_s_setprio(0);                                                      \
    if (DOSTORE) {                                                                      \
      const int dd = d0 + ph_ - 2;                                                      \
      _Pragma("unroll")                                                                 \
      for (int q = 0; q < 2; ++q) {                                                     \
        const int hl = wid, wt = q;                                                     \
        float* op = out + (((size_t)(b * 16 + m) * 64 + dd) * 128 + (h0 + hl)) * 128    \
                    + w0 + wt * 16 + g * 4;                                             \
        *(float4*)op = make_float4(AS[q][0], AS[q][1], AS[q][2], AS[q][3]);             \
        AS[q] = fzero;                                                                  \
      }                                                                                 \
    }                                                                                   \
    __syncthreads();                                                                    \
  }

  // peel: planes 0,1 skip j's that would target out-of-block depths
  BODY(0, A1, A2, A0, 1, 0, 0, 1, 0)
  BODY(1, A2, A0, A1, 1, 1, 0, 1, 0)
  BODY(2, A0, A1, A2, 1, 1, 1, 1, 1)
  #pragma unroll 1
  for (int pp = 3; pp <= 6; pp += 3) {
    BODY(pp,     A1, A2, A0, 1, 1, 1, 1, 1)
    BODY(pp + 1, A2, A0, A1, 1, 1, 1, 1, 1)
    BODY(pp + 2, A0, A1, A2, 1, 1, 1, 1, 1)
  }
  // tail: plane 9 only finishes dout d0+7 (j0); no further loads
  BODY(9, A1, A2, A0, 0, 0, 1, 0, 1)
#undef BODY
}

extern "C" void kernel_launch(void* const* d_in, const int* in_sizes, int n_in,
                              void* d_out, int out_size, void* d_ws, size_t ws_size,
                              hipStream_t stream) {
  (void)in_sizes; (void)n_in; (void)out_size; (void)ws_size;
  const float* x   = (const float*)d_in[0];
  const float* gw  = (const float*)d_in[1];
  const float* gb  = (const float*)d_in[2];
  const float* thr = (const float*)d_in[3];
  const float* cw  = (const float*)d_in[4];
  float* out = (float*)d_out;

  char* ws = (char*)d_ws;
  unsigned short* z = (unsigned short*)ws;                               // 64 MiB bf16
  float2* partials  = (float2*)(ws + (size_t)67108864);                  // 8 KiB
  float2* stats     = (float2*)(ws + (size_t)67108864 + 8192);           // 128 B
  int*    hist      = (int*)  (ws + (size_t)67108864 + 8192 + 128);      // 84 B
  unsigned int* dummy = (unsigned int*)(ws + (size_t)67108864 + 8448);   // 64 B zeros
  unsigned short* fbw2 = (unsigned short*)(ws + (size_t)67108864 + 16384); // 15,360 B

  k1_partials<<<1024, 256, 0, stream>>>(x, partials);
  k2_prep<<<1, 1024, 0, stream>>>(partials, cw, stats, hist, fbw2, dummy);
  k3_norm_thresh_hist<<<1024, 256, 0, stream>>>(x, gw, gb, thr, stats, z, hist);
  k4_conv<<<dim3(64, 8, 2), 512, 0, stream>>>(z, fbw2, (const char*)dummy, hist, out);
}